// Round 15
// baseline (6771.333 us; speedup 1.0000x reference)
//
#include <hip/hip_runtime.h>
#include <hip/hip_bf16.h>

#define T_SEQ 512
#define BATCH 64
#define IN0   128
#define HID   512
#define OUTF  256
#define NWG_L 64          // WGs per layer per step-kernel (each owns 8 units)

typedef __attribute__((ext_vector_type(8))) short short8;   // 8 bf16 (MFMA A/B frag)
typedef __attribute__((ext_vector_type(4))) float f32x4;    // MFMA C/D frag
typedef unsigned short u16;

__device__ __forceinline__ float sigmoidf_(float x) { return 1.f / (1.f + __expf(-x)); }
__device__ __forceinline__ float tanhf_(float x)    { return 1.f - 2.f / (1.f + __expf(2.f * x)); }

__device__ __forceinline__ u16 f2bf(float f) {
    union { float f; unsigned u; } a; a.f = f;
    unsigned u = a.u;
    return (u16)((u + 0x7fffu + ((u >> 16) & 1u)) >> 16);   // RNE
}

// ---------------- f32 -> bf16 conversion ----------------
__global__ void cvt_f32_bf16(const float* __restrict__ in, u16* __restrict__ out, int n4) {
    int i = blockIdx.x * blockDim.x + threadIdx.x;
    if (i < n4) {
        float4 v = reinterpret_cast<const float4*>(in)[i];
        ushort4 o;
        o.x = f2bf(v.x); o.y = f2bf(v.y); o.z = f2bf(v.z); o.w = f2bf(v.w);
        reinterpret_cast<ushort4*>(out)[i] = o;
    }
}

// ---------------- weight repack: f32 -> bf16 in MFMA B-frag order ----------------
// wp[((g*2+nt)*KS + ks)*512 + lane*8 .. +8): 8 bf16 of gate row
// r = (q>>2)*HID + 8g + 4nt + (q&3) (q=lane&15) at col ks*32 + (lane>>4)*8,
// from wih (ks<KS1, width KIN) else whh (width HID).
template<int KS1>
__global__ void repack_w(const float* __restrict__ wih, const float* __restrict__ whh,
                         u16* __restrict__ wp)
{
    constexpr int KS  = KS1 + 16;
    constexpr int KIN = (KS1 == 4) ? IN0 : HID;
    int idx = blockIdx.x * blockDim.x + threadIdx.x;   // one per (g,nt,ks,lane)
    if (idx >= NWG_L * 2 * KS * 64) return;
    int lane = idx & 63;
    int ks   = (idx >> 6) % KS;
    int nt   = ((idx >> 6) / KS) & 1;
    int g    = (idx >> 6) / (KS * 2);
    int q = lane & 15, kq = lane >> 4;
    int r = (q >> 2) * HID + 8 * g + 4 * nt + (q & 3);
    const float* src = (ks < KS1)
        ? wih + (size_t)r * KIN + ks * 32 + kq * 8
        : whh + (size_t)r * HID + (ks - KS1) * 32 + kq * 8;
    u16* dst = wp + (((size_t)(g * 2 + nt) * KS + ks) << 9) + lane * 8;
    #pragma unroll
    for (int j = 0; j < 8; ++j) dst[j] = f2bf(src[j]);
}

// ---------------- one time-step kernel (both layers, pipeline offset 1) --------
// Kernel t: WG 0..63  -> layer 0 step s=t    (skip if s>511)
//           WG 64..127-> layer 1 step s=t-1  (skip if s<0)
// Kernel boundary = device barrier + memory visibility: no flags/polls/atomics.
__global__ __launch_bounds__(256)
void lstm_step(int t,
               const u16* __restrict__ x_bf,
               const u16* __restrict__ wp0, const u16* __restrict__ wp1,
               const float* __restrict__ b0, const float* __restrict__ b1,
               u16* __restrict__ h0buf, u16* __restrict__ h1buf,
               float* __restrict__ cbuf,
               float* __restrict__ hN, float* __restrict__ cN)
{
    __shared__ float lds_g[BATCH][33];
    __shared__ __align__(16) unsigned lds_h[BATCH][4];

    const int wgid = blockIdx.x;
    const int L = (wgid >= NWG_L) ? 1 : 0;
    const int g = L ? wgid - NWG_L : wgid;
    const int s = L ? t - 1 : t;
    if (s < 0 || s >= T_SEQ) return;

    const int tid  = threadIdx.x;
    const int lane = tid & 63;
    const int w    = tid >> 6;
    const int ubase = 8 * g;
    const int arow = 16 * w + (lane & 15);
    const int koff = (lane >> 4) * 8;

    const int KS1 = L ? 16 : 4;
    const int KS  = KS1 + 16;
    const u16* wp       = L ? wp1 : wp0;
    const float* bias   = L ? b1 : b0;
    const u16* ain      = L ? h0buf + (size_t)s * BATCH * HID
                            : x_bf  + (size_t)s * BATCH * IN0;
    const int  ainld    = L ? HID : IN0;
    const u16* hprevbuf = L ? h1buf : h0buf;
    u16*       hout     = L ? h1buf : h0buf;
    float*     cst      = cbuf + (size_t)L * BATCH * HID;

    const u16* wpt0 = wp + (((size_t)(g * 2 + 0) * KS) << 9) + lane * 8;
    const u16* wpt1 = wp + (((size_t)(g * 2 + 1) * KS) << 9) + lane * 8;

    f32x4 ac0[2] = {{0,0,0,0},{0,0,0,0}};
    f32x4 ac1[2] = {{0,0,0,0},{0,0,0,0}};

    // ---- input GEMM (x[s] for L0, y0[s]=h0buf[s] for L1) ----
    {
        const u16* ap = ain + (size_t)arow * ainld + koff;
        for (int ks = 0; ks < KS1; ++ks) {
            short8 a  = *reinterpret_cast<const short8*>(ap + ks * 32);
            short8 f0 = *reinterpret_cast<const short8*>(wpt0 + ((size_t)ks << 9));
            short8 f1 = *reinterpret_cast<const short8*>(wpt1 + ((size_t)ks << 9));
            ac0[ks & 1] = __builtin_amdgcn_mfma_f32_16x16x32_bf16(a, f0, ac0[ks & 1], 0, 0, 0);
            ac1[ks & 1] = __builtin_amdgcn_mfma_f32_16x16x32_bf16(a, f1, ac1[ks & 1], 0, 0, 0);
        }
    }
    // ---- recurrent GEMM h[s-1] ----
    if (s > 0) {
        const u16* hp = hprevbuf + ((size_t)(s - 1) * BATCH + arow) * HID + koff;
        for (int ks = 0; ks < 16; ++ks) {
            short8 a  = *reinterpret_cast<const short8*>(hp + ks * 32);
            short8 f0 = *reinterpret_cast<const short8*>(wpt0 + ((size_t)(KS1 + ks) << 9));
            short8 f1 = *reinterpret_cast<const short8*>(wpt1 + ((size_t)(KS1 + ks) << 9));
            ac0[ks & 1] = __builtin_amdgcn_mfma_f32_16x16x32_bf16(a, f0, ac0[ks & 1], 0, 0, 0);
            ac1[ks & 1] = __builtin_amdgcn_mfma_f32_16x16x32_bf16(a, f1, ac1[ks & 1], 0, 0, 0);
        }
    }

    f32x4 s0 = ac0[0] + ac0[1];
    f32x4 s1 = ac1[0] + ac1[1];
    // D frag: row = 16w + (lane>>4)*4 + j (batch), col = lane&15 (q)
    #pragma unroll
    for (int j = 0; j < 4; ++j) {
        int row = 16 * w + (lane >> 4) * 4 + j;
        lds_g[row][lane & 15]        = s0[j];
        lds_g[row][16 + (lane & 15)] = s1[j];
    }
    __syncthreads();

    // ---- cell update (f32): thread (pb,pu2) owns units 2pu2, 2pu2+1 ----
    {
        const int pb  = tid & 63;
        const int pu2 = tid >> 6;
        const int nt = pu2 >> 1;
        const int dq = (2 * pu2) & 3;
        const int u0 = ubase + 4 * nt + dq, u1 = u0 + 1;
        const float* gr = &lds_g[pb][nt * 16];
        float gi0 = sigmoidf_(gr[dq]      + bias[0 * HID + u0]);
        float gf0 = sigmoidf_(gr[4 + dq]  + bias[1 * HID + u0]);
        float gg0 = tanhf_(   gr[8 + dq]  + bias[2 * HID + u0]);
        float go0 = sigmoidf_(gr[12 + dq] + bias[3 * HID + u0]);
        float gi1 = sigmoidf_(gr[dq + 1]      + bias[0 * HID + u1]);
        float gf1 = sigmoidf_(gr[4 + dq + 1]  + bias[1 * HID + u1]);
        float gg1 = tanhf_(   gr[8 + dq + 1]  + bias[2 * HID + u1]);
        float go1 = sigmoidf_(gr[12 + dq + 1] + bias[3 * HID + u1]);
        float c0 = (s > 0) ? cst[pb * HID + u0] : 0.f;
        float c1 = (s > 0) ? cst[pb * HID + u1] : 0.f;
        c0 = gf0 * c0 + gi0 * gg0;
        c1 = gf1 * c1 + gi1 * gg1;
        float h0v = go0 * tanhf_(c0);
        float h1v = go1 * tanhf_(c1);
        cst[pb * HID + u0] = c0;
        cst[pb * HID + u1] = c1;
        lds_h[pb][pu2] = (unsigned)f2bf(h0v) | ((unsigned)f2bf(h1v) << 16);
        if (s == T_SEQ - 1) {
            float* hNl = hN + (size_t)L * BATCH * HID;
            float* cNl = cN + (size_t)L * BATCH * HID;
            hNl[pb * HID + u0] = h0v;
            hNl[pb * HID + u1] = h1v;
            cNl[pb * HID + u0] = c0;
            cNl[pb * HID + u1] = c1;
        }
    }
    __syncthreads();

    // ---- wave 0: coalesced h publish (plain stores; kernel boundary syncs) ----
    if (w == 0) {
        uint4 hv = *reinterpret_cast<const uint4*>(&lds_h[lane][0]);
        *reinterpret_cast<uint4*>(hout + ((size_t)s * BATCH + lane) * HID + ubase) = hv;
    }
}

// ---------------- final FC: out[32768,256] = y1[32768,512] @ fc_w[256,512]^T + b ----------
__global__ __launch_bounds__(256)
void fc_kernel(const u16* __restrict__ y1, const u16* __restrict__ fcw,
               const float* __restrict__ fcb, float* __restrict__ out)
{
    const int tid  = threadIdx.x;
    const int lane = tid & 63;
    const int wgid = blockIdx.x * 4 + (tid >> 6);  // 0..1023 waves
    const int nq   = wgid & 3;                     // 64-col block
    const int mt0  = wgid >> 2;                    // 0..255

    for (int j = 0; j < 8; ++j) {
        int mt = mt0 + j * 256;                    // M-tile 0..2047
        f32x4 acc[4] = {{0,0,0,0},{0,0,0,0},{0,0,0,0},{0,0,0,0}};
        const u16* arow = y1 + ((size_t)mt * 16 + (lane & 15)) * HID + (lane >> 4) * 8;
        #pragma unroll
        for (int ks = 0; ks < 16; ++ks) {
            short8 a = *reinterpret_cast<const short8*>(arow + ks * 32);
            #pragma unroll
            for (int nt = 0; nt < 4; ++nt) {
                const u16* brow = fcw + ((size_t)(nq * 64 + nt * 16 + (lane & 15))) * HID
                                      + ks * 32 + (lane >> 4) * 8;
                short8 b = *reinterpret_cast<const short8*>(brow);
                acc[nt] = __builtin_amdgcn_mfma_f32_16x16x32_bf16(a, b, acc[nt], 0, 0, 0);
            }
        }
        #pragma unroll
        for (int nt = 0; nt < 4; ++nt) {
            int col = nq * 64 + nt * 16 + (lane & 15);
            float bb = fcb[col];
            #pragma unroll
            for (int jj = 0; jj < 4; ++jj) {
                int row = mt * 16 + (lane >> 4) * 4 + jj;
                out[(size_t)row * OUTF + col] = acc[nt][jj] + bb;
            }
        }
    }
}

extern "C" void kernel_launch(void* const* d_in, const int* in_sizes, int n_in,
                              void* d_out, int out_size, void* d_ws, size_t ws_size,
                              hipStream_t stream)
{
    const float* x    = (const float*)d_in[0];
    const float* wih0 = (const float*)d_in[1];
    const float* whh0 = (const float*)d_in[2];
    const float* b0   = (const float*)d_in[3];
    const float* wih1 = (const float*)d_in[4];
    const float* whh1 = (const float*)d_in[5];
    const float* b1   = (const float*)d_in[6];
    const float* fcw  = (const float*)d_in[7];
    const float* fcb  = (const float*)d_in[8];
    float* out = (float*)d_out;

    char* ws = (char*)d_ws;
    size_t off = 0;
    u16* x_bf   = (u16*)(ws + off);   off += (size_t)T_SEQ * BATCH * IN0 * 2;
    u16* wp0    = (u16*)(ws + off);   off += (size_t)NWG_L * 2 * 20 * 512 * 2;   // KS=20
    u16* wp1    = (u16*)(ws + off);   off += (size_t)NWG_L * 2 * 32 * 512 * 2;   // KS=32
    u16* fcw_bf = (u16*)(ws + off);   off += (size_t)OUTF * HID * 2;
    u16* h0buf  = (u16*)(ws + off);   off += (size_t)T_SEQ * BATCH * HID * 2;
    u16* h1buf  = (u16*)(ws + off);   off += (size_t)T_SEQ * BATCH * HID * 2;
    float* cbuf = (float*)(ws + off); off += (size_t)2 * BATCH * HID * 4;

    {   // one-time prep
        int n4 = (T_SEQ * BATCH * IN0) / 4;
        cvt_f32_bf16<<<(n4 + 255) / 256, 256, 0, stream>>>(x, x_bf, n4);
        n4 = (OUTF * HID) / 4;
        cvt_f32_bf16<<<(n4 + 255) / 256, 256, 0, stream>>>(fcw, fcw_bf, n4);
        int tot0 = NWG_L * 2 * 20 * 64;
        repack_w<4><<<(tot0 + 255) / 256, 256, 0, stream>>>(wih0, whh0, wp0);
        int tot1 = NWG_L * 2 * 32 * 64;
        repack_w<16><<<(tot1 + 255) / 256, 256, 0, stream>>>(wih1, whh1, wp1);
    }

    float* outFC = out;
    float* hN = out + (size_t)T_SEQ * BATCH * OUTF;     // [2,B,H]
    float* cN = hN + 2 * BATCH * HID;                   // [2,B,H]

    for (int t = 0; t <= T_SEQ; ++t)
        lstm_step<<<2 * NWG_L, 256, 0, stream>>>(t, x_bf, wp0, wp1, b0, b1,
                                                 h0buf, h1buf, cbuf, hN, cN);

    fc_kernel<<<256, 256, 0, stream>>>(h1buf, fcw_bf, fcb, outFC);
}

// Round 16
// 3333.403 us; speedup vs baseline: 2.0314x; 2.0314x over previous
//
#include <hip/hip_runtime.h>
#include <hip/hip_bf16.h>

#define T_SEQ 512
#define BATCH 64
#define IN0   128
#define HID   512
#define OUTF  256
#define G4    (4*HID)     // 2048 gate rows
#define NWG_L 64          // workgroups per layer (each owns 8 hidden units)
#define FSTR  32          // u32s between flags -> one 128B line per producer

typedef __attribute__((ext_vector_type(8))) short short8;   // 8 bf16 (MFMA A/B frag)
typedef __attribute__((ext_vector_type(4))) float f32x4;    // MFMA C/D frag
typedef unsigned short u16;
typedef unsigned long long u64;

__device__ __forceinline__ float sigmoidf_(float x) { return 1.f / (1.f + __expf(-x)); }
__device__ __forceinline__ float tanhf_(float x)    { return 1.f - 2.f / (1.f + __expf(2.f * x)); }

__device__ __forceinline__ u16 f2bf(float f) {
    union { float f; unsigned u; } a; a.f = f;
    unsigned u = a.u;
    return (u16)((u + 0x7fffu + ((u >> 16) & 1u)) >> 16);   // RNE
}

// Busy-burn between flag probes: ~64 dependent FMAs (~256 cyc). Keeps the
// SIMD VALU-active while waiting so DVFS holds boost clocks (R16 theory:
// the uniform ~4x hop-latency inflation across all protocol variants is
// idle-clock throttling, not fabric latency).
__device__ __forceinline__ void burn_valu() {
    float a = 1.0f;
    #pragma unroll
    for (int i = 0; i < 64; ++i)
        a = __builtin_fmaf(a, 1.0000001f, 1e-7f);
    asm volatile("" :: "v"(a));   // keep live, no side effect
}

// Groupwise poll (R12/R13 structure): wait for producers [16*grp, 16*grp+16)
// >= tgt. Lane l watches flags[(16*grp + (l&15)) * FSTR]. Busy-burn between
// probes instead of s_sleep; rare acquire as progress safety net.
__device__ __forceinline__ void poll_grp(const unsigned* flags, int lane, int grp, unsigned tgt) {
    const unsigned* p = flags + (size_t)(grp * 16 + (lane & 15)) * FSTR;
    unsigned it = 0;
    for (;;) {
        unsigned v = __hip_atomic_load(p, __ATOMIC_RELAXED, __HIP_MEMORY_SCOPE_AGENT);
        if (__all((int)(v >= tgt))) return;
        burn_valu();
        if ((++it & 1023u) == 0u)
            (void)__hip_atomic_load(p, __ATOMIC_ACQUIRE, __HIP_MEMORY_SCOPE_AGENT);
    }
}

// ---------------- f32 -> bf16 conversion ----------------
__global__ void cvt_f32_bf16(const float* __restrict__ in, u16* __restrict__ out, int n4) {
    int i = blockIdx.x * blockDim.x + threadIdx.x;
    if (i < n4) {
        float4 v = reinterpret_cast<const float4*>(in)[i];
        ushort4 o;
        o.x = f2bf(v.x); o.y = f2bf(v.y); o.z = f2bf(v.z); o.w = f2bf(v.w);
        reinterpret_cast<ushort4*>(out)[i] = o;
    }
}

// ---------------- fused pipelined 2-layer LSTM ----------------
// WG g in [0,64): layer 0, owns hidden units [8g, 8g+8) -> 32 gate rows as 2
// MFMA col-tiles. WG 64+g: layer 1, same ownership.
// flags[g*FSTR] = #steps completed by WG g of that layer.
// Waits are groupwise and self-paced per wave (R12): K-slice group grp
// depends only on producers [16grp,16grp+16); poll -> load 4 slices -> MFMA.
// Publish path identical to R6/R12/R13.
template<int LAYER>
__device__ __forceinline__ void run_layer(
    const u16* __restrict__ asrc,   // L0: x_bf [T,B,128]; L1: y0 [T,B,512]
    const u16* __restrict__ wih, const u16* __restrict__ whh,
    const float* __restrict__ bias,
    u16* __restrict__ ybuf,         // own-layer h/y storage [T,B,512]
    float* __restrict__ hNout, float* __restrict__ cNout,
    unsigned* flags_own, unsigned* flags_dep, int g,
    u16 (*lds_w)[32][512], float (*lds_g)[33], float (*lds_b)[16],
    unsigned (*lds_h)[4])
{
    constexpr int KIN = (LAYER == 0) ? IN0 : HID;
    constexpr int KS1 = KIN / 32;        // input-part K slices
    constexpr int KS  = KS1 + 16;        // + recurrent K slices

    const int tid  = threadIdx.x;
    const int lane = tid & 63;
    const int w    = tid >> 6;           // wave id -> batch rows 16w..16w+15
    const int ubase = 8 * g;

    // ---- pack weights into LDS in MFMA B-frag order (2 col-tiles) ----
    for (int idx = tid; idx < 2 * KS * 64; idx += 256) {
        int nt  = (idx >= KS * 64) ? 1 : 0;
        int rem = idx - nt * KS * 64;
        int ks = rem >> 6, s = rem & 63, q = s & 15, kq = s >> 4;
        int r = (q >> 2) * HID + ubase + 4 * nt + (q & 3);   // global gate row
        const u16* src = (ks < KS1)
            ? wih + (size_t)r * KIN + (size_t)ks * 32 + kq * 8
            : whh + (size_t)r * HID + (size_t)(ks - KS1) * 32 + kq * 8;
        *reinterpret_cast<uint4*>(&lds_w[nt][ks][s * 8]) =
            *reinterpret_cast<const uint4*>(src);
    }
    if (tid < 32) {
        int nt = tid >> 4, q = tid & 15;
        lds_b[nt][q] = bias[(q >> 2) * HID + ubase + 4 * nt + (q & 3)];
    }
    __syncthreads();

    const int pb  = tid & 63;   // pointwise: batch index
    const int pu2 = tid >> 6;   // pointwise: unit-pair index (0..3)
    float c0 = 0.f, c1 = 0.f;

    const int arow = 16 * w + (lane & 15);
    const int koff = (lane >> 4) * 8;

    for (int t = 0; t < T_SEQ; ++t) {
        f32x4 ac0[4] = {{0,0,0,0},{0,0,0,0},{0,0,0,0},{0,0,0,0}};
        f32x4 ac1[4] = {{0,0,0,0},{0,0,0,0},{0,0,0,0},{0,0,0,0}};

        // ---- input contribution ----
        if (LAYER == 0) {
            // x[t]: no dependency
            const u16* ap = asrc + ((size_t)t * BATCH + arow) * KIN + koff;
            short8 a[KS1];
            #pragma unroll
            for (int j = 0; j < KS1; ++j)
                a[j] = *reinterpret_cast<const short8*>(ap + j * 32);
            #pragma unroll
            for (int j = 0; j < KS1; ++j) {
                ac0[j & 3] = __builtin_amdgcn_mfma_f32_16x16x32_bf16(
                    a[j], *reinterpret_cast<const short8*>(&lds_w[0][j][lane * 8]), ac0[j & 3], 0, 0, 0);
                ac1[j & 3] = __builtin_amdgcn_mfma_f32_16x16x32_bf16(
                    a[j], *reinterpret_cast<const short8*>(&lds_w[1][j][lane * 8]), ac1[j & 3], 0, 0, 0);
            }
        } else {
            // y0[t]: groupwise (L0 runs ahead -> polls usually hit first try)
            const u16* ap = asrc + ((size_t)t * BATCH + arow) * HID + koff;
            for (int grp = 0; grp < 4; ++grp) {
                poll_grp(flags_dep, lane, grp, (unsigned)(t + 1));
                #pragma unroll
                for (int j = 0; j < 4; ++j) {
                    int ks = grp * 4 + j;
                    short8 a = *reinterpret_cast<const short8*>(ap + ks * 32);
                    ac0[j] = __builtin_amdgcn_mfma_f32_16x16x32_bf16(
                        a, *reinterpret_cast<const short8*>(&lds_w[0][ks][lane * 8]), ac0[j], 0, 0, 0);
                    ac1[j] = __builtin_amdgcn_mfma_f32_16x16x32_bf16(
                        a, *reinterpret_cast<const short8*>(&lds_w[1][ks][lane * 8]), ac1[j], 0, 0, 0);
                }
            }
        }

        // ---- recurrent contribution h[t-1]: groupwise self-paced ----
        if (t > 0) {
            const u16* hp = ybuf + ((size_t)(t - 1) * BATCH + arow) * HID + koff;
            for (int grp = 0; grp < 4; ++grp) {
                poll_grp(flags_own, lane, grp, (unsigned)t);
                #pragma unroll
                for (int j = 0; j < 4; ++j) {
                    int ks = grp * 4 + j;
                    short8 a = *reinterpret_cast<const short8*>(hp + ks * 32);
                    ac0[j] = __builtin_amdgcn_mfma_f32_16x16x32_bf16(
                        a, *reinterpret_cast<const short8*>(&lds_w[0][KS1 + ks][lane * 8]), ac0[j], 0, 0, 0);
                    ac1[j] = __builtin_amdgcn_mfma_f32_16x16x32_bf16(
                        a, *reinterpret_cast<const short8*>(&lds_w[1][KS1 + ks][lane * 8]), ac1[j], 0, 0, 0);
                }
            }
        }

        f32x4 s0 = (ac0[0] + ac0[1]) + (ac0[2] + ac0[3]);
        f32x4 s1 = (ac1[0] + ac1[1]) + (ac1[2] + ac1[3]);
        // D frag: row = 16w + (lane>>4)*4 + j (batch), col = lane&15 (q)
        #pragma unroll
        for (int j = 0; j < 4; ++j) {
            int row = 16 * w + (lane >> 4) * 4 + j;
            lds_g[row][lane & 15]        = s0[j];
            lds_g[row][16 + (lane & 15)] = s1[j];
        }
        __syncthreads();

        // pointwise cell update (f32): thread (pb,pu2) owns units 2pu2, 2pu2+1
        {
            const int nt = pu2 >> 1;
            const int dq = (2 * pu2) & 3;
            const float* gr = &lds_g[pb][nt * 16];
            const float* br = lds_b[nt];
            float gi0 = sigmoidf_(gr[dq]      + br[dq]);
            float gf0 = sigmoidf_(gr[4 + dq]  + br[4 + dq]);
            float gg0 = tanhf_(   gr[8 + dq]  + br[8 + dq]);
            float go0 = sigmoidf_(gr[12 + dq] + br[12 + dq]);
            c0 = gf0 * c0 + gi0 * gg0;
            float h0v = go0 * tanhf_(c0);
            float gi1 = sigmoidf_(gr[dq + 1]      + br[dq + 1]);
            float gf1 = sigmoidf_(gr[4 + dq + 1]  + br[4 + dq + 1]);
            float gg1 = tanhf_(   gr[8 + dq + 1]  + br[8 + dq + 1]);
            float go1 = sigmoidf_(gr[12 + dq + 1] + br[12 + dq + 1]);
            c1 = gf1 * c1 + gi1 * gg1;
            float h1v = go1 * tanhf_(c1);

            lds_h[pb][pu2] = (unsigned)f2bf(h0v) | ((unsigned)f2bf(h1v) << 16);

            if (t == T_SEQ - 1) {
                const int u0 = ubase + 4 * nt + dq, u1 = u0 + 1;
                hNout[pb * HID + u0] = h0v;
                hNout[pb * HID + u1] = h1v;
                cNout[pb * HID + u0] = c0;
                cNout[pb * HID + u1] = c1;
            }
        }
        __syncthreads();

        // slim publish (R6): wave 0 stores the WG's whole 1KB block (16B/lane
        // as 2x u64 agent stores), waits only its own acks, then lane 0
        // raises the flag. Waves 1-3 run ahead into step t+1.
        if (w == 0) {
            uint4 hv = *reinterpret_cast<const uint4*>(&lds_h[lane][0]);
            u64 q0 = (u64)hv.x | ((u64)hv.y << 32);
            u64 q1 = (u64)hv.z | ((u64)hv.w << 32);
            u64* yp = reinterpret_cast<u64*>(
                ybuf + ((size_t)t * BATCH + lane) * HID + ubase);
            __hip_atomic_store(yp + 0, q0, __ATOMIC_RELAXED, __HIP_MEMORY_SCOPE_AGENT);
            __hip_atomic_store(yp + 1, q1, __ATOMIC_RELAXED, __HIP_MEMORY_SCOPE_AGENT);
            asm volatile("s_waitcnt vmcnt(0)" ::: "memory");
            if (lane == 0)
                __hip_atomic_store(flags_own + (size_t)g * FSTR, (unsigned)(t + 1),
                                   __ATOMIC_RELAXED, __HIP_MEMORY_SCOPE_AGENT);
        }
    }
}

__global__ __launch_bounds__(256, 1)
void lstm_fused(const u16* __restrict__ x_bf,
                const u16* __restrict__ wih0, const u16* __restrict__ whh0, const float* __restrict__ b0,
                const u16* __restrict__ wih1, const u16* __restrict__ whh1, const float* __restrict__ b1,
                u16* __restrict__ y0, u16* __restrict__ y1,
                float* __restrict__ hN, float* __restrict__ cN,
                unsigned* __restrict__ ctr)
{
    __shared__ __align__(16) u16 lds_w[2][32][512];   // 64 KB (L0 uses KS=20 of 32)
    __shared__ float lds_g[BATCH][33];
    __shared__ float lds_b[2][16];
    __shared__ __align__(16) unsigned lds_h[BATCH][4];

    unsigned* flags0 = ctr;
    unsigned* flags1 = ctr + NWG_L * FSTR;

    const int wgid = blockIdx.x;
    if (wgid < NWG_L) {
        run_layer<0>(x_bf, wih0, whh0, b0, y0, hN, cN,
                     flags0, flags0, wgid, lds_w, lds_g, lds_b, lds_h);
    } else {
        run_layer<1>(y0, wih1, whh1, b1, y1, hN + BATCH * HID, cN + BATCH * HID,
                     flags1, flags0, wgid - NWG_L, lds_w, lds_g, lds_b, lds_h);
    }
}

// ---------------- final FC: out[32768,256] = y1[32768,512] @ fc_w[256,512]^T + b ----------
__global__ __launch_bounds__(256)
void fc_kernel(const u16* __restrict__ y1, const u16* __restrict__ fcw,
               const float* __restrict__ fcb, float* __restrict__ out)
{
    const int tid  = threadIdx.x;
    const int lane = tid & 63;
    const int wgid = blockIdx.x * 4 + (tid >> 6);  // 0..1023 waves
    const int nq   = wgid & 3;                     // 64-col block
    const int mt0  = wgid >> 2;                    // 0..255

    for (int j = 0; j < 8; ++j) {
        int mt = mt0 + j * 256;                    // M-tile 0..2047
        f32x4 acc[4] = {{0,0,0,0},{0,0,0,0},{0,0,0,0},{0,0,0,0}};
        const u16* arow = y1 + ((size_t)mt * 16 + (lane & 15)) * HID + (lane >> 4) * 8;
        #pragma unroll
        for (int ks = 0; ks < 16; ++ks) {
            short8 a = *reinterpret_cast<const short8*>(arow + ks * 32);
            #pragma unroll
            for (int nt = 0; nt < 4; ++nt) {
                const u16* brow = fcw + ((size_t)(nq * 64 + nt * 16 + (lane & 15))) * HID
                                      + ks * 32 + (lane >> 4) * 8;
                short8 b = *reinterpret_cast<const short8*>(brow);
                acc[nt] = __builtin_amdgcn_mfma_f32_16x16x32_bf16(a, b, acc[nt], 0, 0, 0);
            }
        }
        #pragma unroll
        for (int nt = 0; nt < 4; ++nt) {
            int col = nq * 64 + nt * 16 + (lane & 15);
            float bb = fcb[col];
            #pragma unroll
            for (int jj = 0; jj < 4; ++jj) {
                int row = mt * 16 + (lane >> 4) * 4 + jj;
                out[(size_t)row * OUTF + col] = acc[nt][jj] + bb;
            }
        }
    }
}

extern "C" void kernel_launch(void* const* d_in, const int* in_sizes, int n_in,
                              void* d_out, int out_size, void* d_ws, size_t ws_size,
                              hipStream_t stream)
{
    const float* x    = (const float*)d_in[0];
    const float* wih0 = (const float*)d_in[1];
    const float* whh0 = (const float*)d_in[2];
    const float* b0   = (const float*)d_in[3];
    const float* wih1 = (const float*)d_in[4];
    const float* whh1 = (const float*)d_in[5];
    const float* b1   = (const float*)d_in[6];
    const float* fcw  = (const float*)d_in[7];
    const float* fcb  = (const float*)d_in[8];
    float* out = (float*)d_out;

    const size_t flag_bytes = (size_t)2 * NWG_L * FSTR * 4;   // 16 KB

    char* ws = (char*)d_ws;
    size_t off = 0;
    unsigned* ctr = (unsigned*)ws;                    off += flag_bytes;
    u16* x_bf    = (u16*)(ws + off);                  off += (size_t)T_SEQ * BATCH * IN0 * 2;
    u16* wih0_bf = (u16*)(ws + off);                  off += (size_t)G4 * IN0 * 2;
    u16* whh0_bf = (u16*)(ws + off);                  off += (size_t)G4 * HID * 2;
    u16* wih1_bf = (u16*)(ws + off);                  off += (size_t)G4 * HID * 2;
    u16* whh1_bf = (u16*)(ws + off);                  off += (size_t)G4 * HID * 2;
    u16* fcw_bf  = (u16*)(ws + off);                  off += (size_t)OUTF * HID * 2;
    u16* y0      = (u16*)(ws + off);                  off += (size_t)T_SEQ * BATCH * HID * 2;
    u16* y1      = (u16*)(ws + off);                  off += (size_t)T_SEQ * BATCH * HID * 2;

    hipMemsetAsync(ctr, 0, flag_bytes, stream);

    auto conv = [&](const float* in, u16* o, int n) {
        int n4 = n / 4;
        cvt_f32_bf16<<<(n4 + 255) / 256, 256, 0, stream>>>(in, o, n4);
    };
    conv(x,    x_bf,    T_SEQ * BATCH * IN0);
    conv(wih0, wih0_bf, G4 * IN0);
    conv(whh0, whh0_bf, G4 * HID);
    conv(wih1, wih1_bf, G4 * HID);
    conv(whh1, whh1_bf, G4 * HID);
    conv(fcw,  fcw_bf,  OUTF * HID);

    float* outFC = out;
    float* hN = out + (size_t)T_SEQ * BATCH * OUTF;     // [2,B,H]
    float* cN = hN + 2 * BATCH * HID;                   // [2,B,H]

    lstm_fused<<<2 * NWG_L, 256, 0, stream>>>(x_bf, wih0_bf, whh0_bf, b0,
                                              wih1_bf, whh1_bf, b1,
                                              y0, y1, hN, cN, ctr);
    fc_kernel<<<256, 256, 0, stream>>>(y1, fcw_bf, fcb, outFC);
}